// Round 1
// baseline (378.452 us; speedup 1.0000x reference)
//
#include <hip/hip_runtime.h>

typedef __bf16 bf16x8 __attribute__((ext_vector_type(8)));
typedef float f32x4 __attribute__((ext_vector_type(4)));
typedef unsigned short ushort8 __attribute__((ext_vector_type(8)));
typedef unsigned short u16;

#define MFMA16(a, b, c) __builtin_amdgcn_mfma_f32_16x16x32_bf16(a, b, c, 0, 0, 0)

__device__ __forceinline__ u16 f2bf(float v) {
  unsigned int u = __builtin_bit_cast(unsigned int, v);
  u += 0x7fffu + ((u >> 16) & 1u);   // RNE; inputs are finite
  return (u16)(u >> 16);
}

__device__ __forceinline__ void gload16(const u16* g, u16* l) {
  __builtin_amdgcn_global_load_lds((__attribute__((address_space(1))) void*)(g),
                                   (__attribute__((address_space(3))) void*)(l), 16, 0, 0);
}

// ---------------- converts ----------------

// 8 f32 -> 8 bf16 per thread; grid*256*8 == count exactly
__global__ __launch_bounds__(256) void conv_x_kernel(const float* __restrict__ in, u16* __restrict__ out) {
  size_t i = (size_t)blockIdx.x * 256 + threadIdx.x;
  const float4* p = (const float4*)in + i * 2;
  float4 a = p[0], b = p[1];
  ushort8 o;
  o[0] = f2bf(a.x); o[1] = f2bf(a.y); o[2] = f2bf(a.z); o[3] = f2bf(a.w);
  o[4] = f2bf(b.x); o[5] = f2bf(b.y); o[6] = f2bf(b.z); o[7] = f2bf(b.w);
  *((ushort8*)out + i) = o;
}

// W: K x N (f32) -> WT: N x K (bf16). Coalesced writes; scattered reads hit L3.
__global__ __launch_bounds__(256) void conv_wT(const float* __restrict__ W, u16* __restrict__ WT,
                                               int K, int N) {
  int idx = blockIdx.x * 256 + threadIdx.x;
  int n = idx / K, k = idx - n * K;
  WT[idx] = f2bf(W[(size_t)k * N + n]);
}

__global__ __launch_bounds__(256) void conv_a_kernel(const float* __restrict__ in, u16* __restrict__ out) {
  int i = blockIdx.x * 256 + threadIdx.x;   // exact 131072
  out[i] = f2bf(in[i] * 0.125f);            // SCALE = 64^-0.5
}

// ---------------- GEMM (A row-major M x K, BT row-major N x K), bf16 in, f32 acc ----------------
// 128x128 tile, BK=32, 256 thr = 4 waves (2x2), each wave 64x64 = 4x4 frags of 16x16x32.
// MODE 0: scatter C (bf16) into q/k/v buffers laid out (b,h,n,d).  MODE 1: f32 row-major out.
template <int MODE>
__global__ __launch_bounds__(256) void gemm_bt(const u16* __restrict__ A, const u16* __restrict__ BT,
                                               int M, int N, int K,
                                               u16* __restrict__ qb, u16* __restrict__ kb,
                                               u16* __restrict__ vb, float* __restrict__ outf) {
  __shared__ u16 As[128][32];
  __shared__ u16 Bs[128][32];
  int ntiles = N >> 7;
  int bx = blockIdx.x;
  int tm = bx / ntiles, tn = bx - tm * ntiles;
  int rb = tm << 7, cb = tn << 7;
  int t = threadIdx.x, w = t >> 6, l = t & 63, lg = l >> 4, li = l & 15;
  int wr = (w >> 1) * 64, wc = (w & 1) * 64;

  f32x4 acc[4][4];
#pragma unroll
  for (int m = 0; m < 4; ++m)
#pragma unroll
    for (int n = 0; n < 4; ++n) acc[m][n] = (f32x4){0.f, 0.f, 0.f, 0.f};

  int kit = K >> 5;
  for (int kt = 0; kt < kit; ++kt) {
    int kof = kt << 5;
#pragma unroll
    for (int c = 0; c < 2; ++c) {
      int rowl = w * 32 + c * 16 + (l >> 2);
      const u16* gA = A + (size_t)(rb + rowl) * K + kof + (l & 3) * 8;
      gload16(gA, &As[w * 32 + c * 16][0]);
      const u16* gB = BT + (size_t)(cb + rowl) * K + kof + (l & 3) * 8;
      gload16(gB, &Bs[w * 32 + c * 16][0]);
    }
    __syncthreads();
    bf16x8 af[4], bf_[4];
#pragma unroll
    for (int m = 0; m < 4; ++m) af[m] = *(const bf16x8*)&As[wr + m * 16 + li][lg * 8];
#pragma unroll
    for (int n = 0; n < 4; ++n) bf_[n] = *(const bf16x8*)&Bs[wc + n * 16 + li][lg * 8];
#pragma unroll
    for (int m = 0; m < 4; ++m)
#pragma unroll
      for (int n = 0; n < 4; ++n) acc[m][n] = MFMA16(af[m], bf_[n], acc[m][n]);
    __syncthreads();
  }

#pragma unroll
  for (int m = 0; m < 4; ++m)
#pragma unroll
    for (int n = 0; n < 4; ++n) {
      int row0 = rb + wr + m * 16 + lg * 4;
      int col = cb + wc + n * 16 + li;
      if (MODE == 0) {
        int s = col >> 10, hh = (col >> 6) & 15, d = col & 63;
        u16* dst = (s == 0) ? qb : ((s == 1) ? kb : vb);
#pragma unroll
        for (int r = 0; r < 4; ++r) {
          int rr = row0 + r;
          int bb = rr >> 12, nn = rr & 4095;
          dst[(((size_t)bb * 16 + hh) * 4096 + nn) * 64 + d] = f2bf(acc[m][n][r]);
        }
      } else {
#pragma unroll
        for (int r = 0; r < 4; ++r) outf[(size_t)(row0 + r) * N + col] = acc[m][n][r];
      }
    }
}

// ---------------- V transpose: (bh, n, 64) -> (bh, 64, n) ----------------
__global__ __launch_bounds__(256) void transpose_v(const u16* __restrict__ v, u16* __restrict__ vt) {
  __shared__ u16 tile[64][72];
  int bid = blockIdx.x;
  int bh = bid >> 6, n0 = (bid & 63) << 6;
  int t = threadIdx.x;
  int nl = t >> 2, ds = (t & 3) << 4;
  const u16* src = v + ((size_t)bh * 4096 + n0 + nl) * 64 + ds;
  *(uint4*)&tile[nl][ds] = *(const uint4*)src;
  *(uint4*)&tile[nl][ds + 8] = *(const uint4*)(src + 8);
  __syncthreads();
  int d = t >> 2, ns = (t & 3) << 4;
  ushort8 o0, o1;
#pragma unroll
  for (int e = 0; e < 8; ++e) { o0[e] = tile[ns + e][d]; o1[e] = tile[ns + 8 + e][d]; }
  u16* dst = vt + ((size_t)bh * 64 + d) * 4096 + n0 + ns;
  *(ushort8*)dst = o0;
  *(ushort8*)(dst + 8) = o1;
}

// ---------------- agent<-key flash attention (softmax over n), 8-way n-split ----------------
// grid 4*16*8; block 256 (4 waves, each owns 32 agent rows). Writes unnormalized partials.
__global__ __launch_bounds__(256) void ak_flash(const u16* __restrict__ kb, const u16* __restrict__ vt,
                                                const u16* __restrict__ ab,
                                                float* __restrict__ pO, float* __restrict__ pM,
                                                float* __restrict__ pL) {
  __shared__ u16 p_lds[128][136];
  int bid = blockIdx.x;
  int s = bid & 7;
  int bh = bid >> 3;
  int h = bh & 15;
  int t = threadIdx.x, w = t >> 6, l = t & 63, lg = l >> 4, li = l & 15;
  int jb = w * 32;

  bf16x8 afr[2][2];
#pragma unroll
  for (int jt = 0; jt < 2; ++jt)
#pragma unroll
    for (int kk = 0; kk < 2; ++kk)
      afr[jt][kk] = *(const bf16x8*)&ab[(size_t)(h * 128 + jb + jt * 16 + li) * 64 + kk * 32 + lg * 8];

  f32x4 O[2][4];
  float mrow[2][4], lrow[2][4];
#pragma unroll
  for (int jt = 0; jt < 2; ++jt) {
#pragma unroll
    for (int dt = 0; dt < 4; ++dt) O[jt][dt] = (f32x4){0.f, 0.f, 0.f, 0.f};
#pragma unroll
    for (int r = 0; r < 4; ++r) { mrow[jt][r] = -1e30f; lrow[jt][r] = 0.f; }
  }
  const u16* kbase = kb + (size_t)bh * 4096 * 64;
  const u16* vbase = vt + (size_t)bh * 64 * 4096;

  for (int c = 0; c < 4; ++c) {
    int i0 = s * 512 + c * 128;
    f32x4 sf[2][8];
#pragma unroll
    for (int jt = 0; jt < 2; ++jt)
#pragma unroll
      for (int it = 0; it < 8; ++it) sf[jt][it] = (f32x4){0.f, 0.f, 0.f, 0.f};
#pragma unroll
    for (int it = 0; it < 8; ++it)
#pragma unroll
      for (int kk = 0; kk < 2; ++kk) {
        bf16x8 bfr = *(const bf16x8*)&kbase[(size_t)(i0 + it * 16 + li) * 64 + kk * 32 + lg * 8];
        sf[0][it] = MFMA16(afr[0][kk], bfr, sf[0][it]);
        sf[1][it] = MFMA16(afr[1][kk], bfr, sf[1][it]);
      }
    // online softmax per row (jt, r); row owned by the 16 lanes sharing lg
#pragma unroll
    for (int jt = 0; jt < 2; ++jt)
#pragma unroll
      for (int r = 0; r < 4; ++r) {
        float cm = sf[jt][0][r];
#pragma unroll
        for (int it = 1; it < 8; ++it) cm = fmaxf(cm, sf[jt][it][r]);
#pragma unroll
        for (int off = 1; off < 16; off <<= 1) cm = fmaxf(cm, __shfl_xor(cm, off));
        float mold = mrow[jt][r];
        float mnew = fmaxf(mold, cm);
        float scale = __expf(mold - mnew);
        float ss = 0.f;
#pragma unroll
        for (int it = 0; it < 8; ++it) {
          float p = __expf(sf[jt][it][r] - mnew);
          sf[jt][it][r] = p;
          ss += p;
        }
#pragma unroll
        for (int off = 1; off < 16; off <<= 1) ss += __shfl_xor(ss, off);
        lrow[jt][r] = lrow[jt][r] * scale + ss;
        mrow[jt][r] = mnew;
#pragma unroll
        for (int dt = 0; dt < 4; ++dt) O[jt][dt][r] *= scale;
      }
    // P -> LDS (wave-private rows; same-wave RAW ordered by lgkmcnt)
#pragma unroll
    for (int jt = 0; jt < 2; ++jt)
#pragma unroll
      for (int it = 0; it < 8; ++it)
#pragma unroll
        for (int r = 0; r < 4; ++r)
          p_lds[jb + jt * 16 + lg * 4 + r][it * 16 + li] = f2bf(sf[jt][it][r]);
    // PV: O[j][d] += P[j][i] * Vt[d][i]
#pragma unroll
    for (int ks = 0; ks < 4; ++ks) {
      bf16x8 pa0 = *(const bf16x8*)&p_lds[jb + li][ks * 32 + lg * 8];
      bf16x8 pa1 = *(const bf16x8*)&p_lds[jb + 16 + li][ks * 32 + lg * 8];
#pragma unroll
      for (int dt = 0; dt < 4; ++dt) {
        bf16x8 bv = *(const bf16x8*)&vbase[(size_t)(dt * 16 + li) * 4096 + i0 + ks * 32 + lg * 8];
        O[0][dt] = MFMA16(pa0, bv, O[0][dt]);
        O[1][dt] = MFMA16(pa1, bv, O[1][dt]);
      }
    }
  }
  size_t pb = ((size_t)bh * 8 + s) * 128;
#pragma unroll
  for (int jt = 0; jt < 2; ++jt)
#pragma unroll
    for (int dt = 0; dt < 4; ++dt)
#pragma unroll
      for (int r = 0; r < 4; ++r) {
        int j = jb + jt * 16 + lg * 4 + r;
        pO[(pb + j) * 64 + dt * 16 + li] = O[jt][dt][r];
      }
  if (li == 0) {
#pragma unroll
    for (int jt = 0; jt < 2; ++jt)
#pragma unroll
      for (int r = 0; r < 4; ++r) {
        int j = jb + jt * 16 + lg * 4 + r;
        pM[pb + j] = mrow[jt][r];
        pL[pb + j] = lrow[jt][r];
      }
  }
}

// combine split partials -> out1t (bh, d, j) bf16 (transposed for MFMA B-frag reads)
__global__ __launch_bounds__(128) void ak_combine(const float* __restrict__ pO, const float* __restrict__ pM,
                                                  const float* __restrict__ pL, u16* __restrict__ out1t) {
  int bh = blockIdx.x;
  int j = threadIdx.x;  // 128
  float ms[8], wv[8];
  float M = -1e30f;
#pragma unroll
  for (int s = 0; s < 8; ++s) { ms[s] = pM[((size_t)bh * 8 + s) * 128 + j]; M = fmaxf(M, ms[s]); }
  float L = 0.f;
#pragma unroll
  for (int s = 0; s < 8; ++s) { wv[s] = __expf(ms[s] - M); L += wv[s] * pL[((size_t)bh * 8 + s) * 128 + j]; }
  float inv = 1.f / L;
  for (int d = 0; d < 64; ++d) {
    float acc = 0.f;
#pragma unroll
    for (int s = 0; s < 8; ++s) acc += wv[s] * pO[(((size_t)bh * 8 + s) * 128 + j) * 64 + d];
    out1t[((size_t)bh * 64 + d) * 128 + j] = f2bf(acc * inv);
  }
}

// ---------------- q<-agent attention fused with P@out1, writes out2 (b, n, h*64+d) bf16 ----------------
// grid 4*16*32; block 256 (4 waves, each owns 32 token rows)
__global__ __launch_bounds__(256) void qa_fused(const u16* __restrict__ qb, const u16* __restrict__ out1t,
                                                const u16* __restrict__ ab, u16* __restrict__ out2) {
  __shared__ u16 p_lds[128][136];
  int bid = blockIdx.x;
  int nt = bid & 31;
  int bh = bid >> 5;
  int h = bh & 15, b = bh >> 4;
  int t = threadIdx.x, w = t >> 6, l = t & 63, lg = l >> 4, li = l & 15;
  int n0 = nt * 128;

  const u16* qbase = qb + ((size_t)bh * 4096 + n0 + w * 32) * 64;
  bf16x8 qf[2][2];
#pragma unroll
  for (int rt = 0; rt < 2; ++rt)
#pragma unroll
    for (int kk = 0; kk < 2; ++kk)
      qf[rt][kk] = *(const bf16x8*)&qbase[(size_t)(rt * 16 + li) * 64 + kk * 32 + lg * 8];

  f32x4 sf[2][8];
#pragma unroll
  for (int rt = 0; rt < 2; ++rt)
#pragma unroll
    for (int jt = 0; jt < 8; ++jt) sf[rt][jt] = (f32x4){0.f, 0.f, 0.f, 0.f};

  const u16* abase = ab + h * 128 * 64;
#pragma unroll
  for (int jt = 0; jt < 8; ++jt)
#pragma unroll
    for (int kk = 0; kk < 2; ++kk) {
      bf16x8 bfr = *(const bf16x8*)&abase[(size_t)(jt * 16 + li) * 64 + kk * 32 + lg * 8];
      sf[0][jt] = MFMA16(qf[0][kk], bfr, sf[0][jt]);
      sf[1][jt] = MFMA16(qf[1][kk], bfr, sf[1][jt]);
    }
  // full softmax over j (128) per row (rt, r); fold 1/sum into the PV epilogue
  float inv[2][4];
#pragma unroll
  for (int rt = 0; rt < 2; ++rt)
#pragma unroll
    for (int r = 0; r < 4; ++r) {
      float cm = sf[rt][0][r];
#pragma unroll
      for (int jt = 1; jt < 8; ++jt) cm = fmaxf(cm, sf[rt][jt][r]);
#pragma unroll
      for (int off = 1; off < 16; off <<= 1) cm = fmaxf(cm, __shfl_xor(cm, off));
      float ss = 0.f;
#pragma unroll
      for (int jt = 0; jt < 8; ++jt) {
        float p = __expf(sf[rt][jt][r] - cm);
        sf[rt][jt][r] = p;
        ss += p;
      }
#pragma unroll
      for (int off = 1; off < 16; off <<= 1) ss += __shfl_xor(ss, off);
      inv[rt][r] = 1.f / ss;
    }
#pragma unroll
  for (int rt = 0; rt < 2; ++rt)
#pragma unroll
    for (int jt = 0; jt < 8; ++jt)
#pragma unroll
      for (int r = 0; r < 4; ++r)
        p_lds[w * 32 + rt * 16 + lg * 4 + r][jt * 16 + li] = f2bf(sf[rt][jt][r]);

  f32x4 O[2][4];
#pragma unroll
  for (int rt = 0; rt < 2; ++rt)
#pragma unroll
    for (int dt = 0; dt < 4; ++dt) O[rt][dt] = (f32x4){0.f, 0.f, 0.f, 0.f};

  const u16* obase = out1t + (size_t)bh * 64 * 128;
#pragma unroll
  for (int ks = 0; ks < 4; ++ks) {
    bf16x8 pa0 = *(const bf16x8*)&p_lds[w * 32 + li][ks * 32 + lg * 8];
    bf16x8 pa1 = *(const bf16x8*)&p_lds[w * 32 + 16 + li][ks * 32 + lg * 8];
#pragma unroll
    for (int dt = 0; dt < 4; ++dt) {
      bf16x8 bv = *(const bf16x8*)&obase[(size_t)(dt * 16 + li) * 128 + ks * 32 + lg * 8];
      O[0][dt] = MFMA16(pa0, bv, O[0][dt]);
      O[1][dt] = MFMA16(pa1, bv, O[1][dt]);
    }
  }
#pragma unroll
  for (int rt = 0; rt < 2; ++rt)
#pragma unroll
    for (int dt = 0; dt < 4; ++dt)
#pragma unroll
      for (int r = 0; r < 4; ++r) {
        int nn = n0 + w * 32 + rt * 16 + lg * 4 + r;
        int col = h * 64 + dt * 16 + li;
        out2[((size_t)b * 4096 + nn) * 1024 + col] = f2bf(O[rt][dt][r] * inv[rt][r]);
      }
}

// ---------------- launch ----------------
extern "C" void kernel_launch(void* const* d_in, const int* in_sizes, int n_in,
                              void* d_out, int out_size, void* d_ws, size_t ws_size,
                              hipStream_t stream) {
  const float* x = (const float*)d_in[0];      // 4*4096*1024
  const float* Wqkv = (const float*)d_in[1];   // 1024*3072
  const float* agent = (const float*)d_in[2];  // 16*128*64
  const float* Wout = (const float*)d_in[3];   // 1024*1024
  float* out = (float*)d_out;                  // 16384*1024 f32

  char* ws = (char*)d_ws;
  u16* x_bf  = (u16*)(ws + 0);           // 32 MB; reused as out2 after GEMM1 consumes it
  u16* wqkvT = (u16*)(ws + 33554432);    // 6 MB
  u16* woutT = (u16*)(ws + 39845888);    // 2 MB
  u16* a_bf  = (u16*)(ws + 41943040);    // 256 KB
  u16* qb    = (u16*)(ws + 42205184);    // 32 MB
  u16* kb    = (u16*)(ws + 75759616);    // 32 MB
  u16* vb    = (u16*)(ws + 109314048);   // 32 MB
  u16* vt    = (u16*)(ws + 142868480);   // 32 MB
  float* pO  = (float*)(ws + 176422912); // 16 MB
  float* pM  = (float*)(ws + 193200128); // 512 KB
  float* pL  = (float*)(ws + 193724416); // 512 KB
  u16* out1t = (u16*)(ws + 194248704);   // 1 MB   (end ~186.3 MiB)
  u16* out2  = x_bf;

  conv_x_kernel<<<8192, 256, 0, stream>>>(x, x_bf);                  // 16.7M elems
  conv_wT<<<12288, 256, 0, stream>>>(Wqkv, wqkvT, 1024, 3072);
  conv_wT<<<4096, 256, 0, stream>>>(Wout, woutT, 1024, 1024);
  conv_a_kernel<<<512, 256, 0, stream>>>(agent, a_bf);

  gemm_bt<0><<<3072, 256, 0, stream>>>(x_bf, wqkvT, 16384, 3072, 1024, qb, kb, vb, nullptr);
  transpose_v<<<4096, 256, 0, stream>>>(vb, vt);
  ak_flash<<<512, 256, 0, stream>>>(kb, vt, a_bf, pO, pM, pL);
  ak_combine<<<64, 128, 0, stream>>>(pO, pM, pL, out1t);
  qa_fused<<<2048, 256, 0, stream>>>(qb, out1t, a_bf, out2);
  gemm_bt<1><<<1024, 256, 0, stream>>>(out2, woutT, 16384, 1024, 1024, nullptr, nullptr, nullptr, out);
}

// Round 2
// 303.243 us; speedup vs baseline: 1.2480x; 1.2480x over previous
//
#include <hip/hip_runtime.h>

typedef __bf16 bf16x8 __attribute__((ext_vector_type(8)));
typedef float f32x4 __attribute__((ext_vector_type(4)));
typedef unsigned short ushort8 __attribute__((ext_vector_type(8)));
typedef unsigned short u16;

#define MFMA16(a, b, c) __builtin_amdgcn_mfma_f32_16x16x32_bf16(a, b, c, 0, 0, 0)
#define VMCNT(n) asm volatile("s_waitcnt vmcnt(" #n ")" ::: "memory")
#define SBAR() do { __builtin_amdgcn_sched_barrier(0); asm volatile("" ::: "memory"); \
                    __builtin_amdgcn_s_barrier(); \
                    asm volatile("" ::: "memory"); __builtin_amdgcn_sched_barrier(0); } while (0)

__device__ __forceinline__ u16 f2bf(float v) {
  unsigned int u = __builtin_bit_cast(unsigned int, v);
  u += 0x7fffu + ((u >> 16) & 1u);   // RNE; inputs are finite
  return (u16)(u >> 16);
}

__device__ __forceinline__ void gload16(const u16* g, u16* l) {
  __builtin_amdgcn_global_load_lds((__attribute__((address_space(1))) void*)(g),
                                   (__attribute__((address_space(3))) void*)(l), 16, 0, 0);
}

// ---------------- converts ----------------

__global__ __launch_bounds__(256) void conv_x_kernel(const float* __restrict__ in, u16* __restrict__ out) {
  size_t i = (size_t)blockIdx.x * 256 + threadIdx.x;
  const float4* p = (const float4*)in + i * 2;
  float4 a = p[0], b = p[1];
  ushort8 o;
  o[0] = f2bf(a.x); o[1] = f2bf(a.y); o[2] = f2bf(a.z); o[3] = f2bf(a.w);
  o[4] = f2bf(b.x); o[5] = f2bf(b.y); o[6] = f2bf(b.z); o[7] = f2bf(b.w);
  *((ushort8*)out + i) = o;
}

// W: K x N (f32) -> WT: N x K (bf16), LDS-tiled 64x64, coalesced both sides.
__global__ __launch_bounds__(256) void conv_wT_tiled(const float* __restrict__ W, u16* __restrict__ WT,
                                                     int K, int N) {
  __shared__ float tile[64][65];
  int nt = N >> 6;
  int kt = blockIdx.x / nt, nti = blockIdx.x - kt * nt;
  int k0 = kt << 6, n0 = nti << 6;
  int t = threadIdx.x;
  int r = t >> 4, c4 = (t & 15) << 2;
#pragma unroll
  for (int j = 0; j < 4; ++j) {
    float4 v = *(const float4*)&W[(size_t)(k0 + j * 16 + r) * N + n0 + c4];
    tile[j * 16 + r][c4] = v.x; tile[j * 16 + r][c4 + 1] = v.y;
    tile[j * 16 + r][c4 + 2] = v.z; tile[j * 16 + r][c4 + 3] = v.w;
  }
  __syncthreads();
  int rn = t >> 2, cs = (t & 3) << 4;
  ushort8 o0, o1;
#pragma unroll
  for (int e = 0; e < 8; ++e) { o0[e] = f2bf(tile[cs + e][rn]); o1[e] = f2bf(tile[cs + 8 + e][rn]); }
  u16* dst = WT + (size_t)(n0 + rn) * K + k0 + cs;
  *(ushort8*)dst = o0;
  *(ushort8*)(dst + 8) = o1;
}

__global__ __launch_bounds__(256) void conv_a_kernel(const float* __restrict__ in, u16* __restrict__ out) {
  int i = blockIdx.x * 256 + threadIdx.x;
  out[i] = f2bf(in[i] * 0.125f);
}

// ---------------- 256^2 deep-pipelined GEMM ----------------
// A: M x K row-major bf16, BT: N x K row-major bf16. 512 thr = 8 waves (2Mx4N),
// per-wave C = 128x64 (acc[8][4] f32x4). BK=32. LDS ring: 4 K-tile slots x (16KB A + 16KB B).
// Stage tile t+3 during tile t; vmcnt(8) once per K-tile; tail 4/0.
// LDS swizzle: L ^= ((L>>7)&3)<<4 (16B-granule; row bits 2:1 into chunk bits) on
// BOTH global-source (inverse) and ds_read side; gload_lds dest stays linear.
// MODE 0: scatter bf16 C into q/k/v (b,h,n,d). MODE 1: f32 row-major out.
template <int MODE>
__global__ __launch_bounds__(512, 2) void gemm256(const u16* __restrict__ A, const u16* __restrict__ BT,
                                                  int M, int N, int K,
                                                  u16* __restrict__ qb, u16* __restrict__ kb,
                                                  u16* __restrict__ vb, float* __restrict__ outf) {
  extern __shared__ char smem[];   // 131072 bytes
  const int NT = K >> 5;
  int ntiles = N >> 8;
  int nwg = (M >> 8) * ntiles;
  int bid = blockIdx.x;
  int wg = (bid & 7) * (nwg >> 3) + (bid >> 3);   // XCD swizzle; nwg % 8 == 0 here
  int tm = wg / ntiles, tn = wg - tm * ntiles;
  int rb = tm << 8, cb = tn << 8;
  int t = threadIdx.x;
  int w = t >> 6, lane = t & 63, li = lane & 15, lg = lane >> 4;
  int wr = w >> 2, wc = w & 3;

  // stage source pointers (inverse-swizzled global addresses), advance 32 elems/tile
  const u16* srcA[2];
  const u16* srcB[2];
#pragma unroll
  for (int j = 0; j < 2; ++j) {
    int D = j * 8192 + t * 16;
    int L = D ^ (((D >> 7) & 3) << 4);
    int row = L >> 6, inb = L & 63;
    srcA[j] = A + (size_t)(rb + row) * K + (inb >> 1);
    srcB[j] = BT + (size_t)(cb + row) * K + (inb >> 1);
  }
#define STAGE_A(slot, kt) do { \
    gload16(srcA[0] + (kt) * 32, (u16*)(smem + (slot) * 32768 + t * 16)); \
    gload16(srcA[1] + (kt) * 32, (u16*)(smem + (slot) * 32768 + 8192 + t * 16)); } while (0)
#define STAGE_B(slot, kt) do { \
    gload16(srcB[0] + (kt) * 32, (u16*)(smem + (slot) * 32768 + 16384 + t * 16)); \
    gload16(srcB[1] + (kt) * 32, (u16*)(smem + (slot) * 32768 + 24576 + t * 16)); } while (0)

  // swizzled ds_read offsets (constant per thread)
  int offA[8], offB[4];
#pragma unroll
  for (int m8 = 0; m8 < 8; ++m8) {
    int row = wr * 128 + m8 * 16 + li;
    int L = row * 64 + lg * 16;
    offA[m8] = L ^ (((L >> 7) & 3) << 4);
  }
#pragma unroll
  for (int n = 0; n < 4; ++n) {
    int row = wc * 64 + n * 16 + li;
    int L = row * 64 + lg * 16;
    offB[n] = 16384 + (L ^ (((L >> 7) & 3) << 4));
  }

  f32x4 acc[8][4];
#pragma unroll
  for (int m = 0; m < 8; ++m)
#pragma unroll
    for (int n = 0; n < 4; ++n) acc[m][n] = (f32x4){0.f, 0.f, 0.f, 0.f};
  bf16x8 afr[4], bfr[4];

#define TILE_BODY(tt, DOSTG, WAITOP) do { \
    char* sb = smem + ((tt) & 3) * 32768; \
    afr[0] = *(const bf16x8*)(sb + offA[0]); \
    afr[1] = *(const bf16x8*)(sb + offA[1]); \
    afr[2] = *(const bf16x8*)(sb + offA[2]); \
    afr[3] = *(const bf16x8*)(sb + offA[3]); \
    bfr[0] = *(const bf16x8*)(sb + offB[0]); \
    bfr[1] = *(const bf16x8*)(sb + offB[1]); \
    bfr[2] = *(const bf16x8*)(sb + offB[2]); \
    bfr[3] = *(const bf16x8*)(sb + offB[3]); \
    if (DOSTG) STAGE_A(((tt) + 3) & 3, (tt) + 3); \
    SBAR(); \
    __builtin_amdgcn_s_setprio(1); \
    _Pragma("unroll") for (int m = 0; m < 4; ++m) \
      _Pragma("unroll") for (int n = 0; n < 4; ++n) acc[m][n] = MFMA16(afr[m], bfr[n], acc[m][n]); \
    __builtin_amdgcn_s_setprio(0); \
    SBAR(); \
    afr[0] = *(const bf16x8*)(sb + offA[4]); \
    afr[1] = *(const bf16x8*)(sb + offA[5]); \
    afr[2] = *(const bf16x8*)(sb + offA[6]); \
    afr[3] = *(const bf16x8*)(sb + offA[7]); \
    if (DOSTG) STAGE_B(((tt) + 3) & 3, (tt) + 3); \
    WAITOP; \
    SBAR(); \
    __builtin_amdgcn_s_setprio(1); \
    _Pragma("unroll") for (int m = 0; m < 4; ++m) \
      _Pragma("unroll") for (int n = 0; n < 4; ++n) acc[4 + m][n] = MFMA16(afr[m], bfr[n], acc[4 + m][n]); \
    __builtin_amdgcn_s_setprio(0); \
    SBAR(); \
  } while (0)

  // prologue: stage tiles 0,1,2 (12 loads); tile0 done when <=8 outstanding
  STAGE_A(0, 0); STAGE_B(0, 0);
  STAGE_A(1, 1); STAGE_B(1, 1);
  STAGE_A(2, 2); STAGE_B(2, 2);
  VMCNT(8);
  SBAR();

  for (int tt = 0; tt <= NT - 4; ++tt) TILE_BODY(tt, true, VMCNT(8));
  TILE_BODY(NT - 3, false, VMCNT(4));
  TILE_BODY(NT - 2, false, VMCNT(0));
  TILE_BODY(NT - 1, false, (void)0);

  if (MODE == 0) {
    int col0 = cb + wc * 64;
    int s = col0 >> 10, hh = (col0 >> 6) & 15;
    u16* dst = (s == 0) ? qb : ((s == 1) ? kb : vb);
#pragma unroll
    for (int m = 0; m < 8; ++m) {
      int rbase = rb + wr * 128 + m * 16 + lg * 4;
#pragma unroll
      for (int r = 0; r < 4; ++r) {
        int rr = rbase + r;
        size_t o = (((size_t)(rr >> 12) * 16 + hh) * 4096 + (rr & 4095)) * 64;
#pragma unroll
        for (int n = 0; n < 4; ++n) dst[o + n * 16 + li] = f2bf(acc[m][n][r]);
      }
    }
  } else {
#pragma unroll
    for (int m = 0; m < 8; ++m) {
#pragma unroll
      for (int r = 0; r < 4; ++r) {
        float* po = outf + (size_t)(rb + wr * 128 + m * 16 + lg * 4 + r) * N + cb + wc * 64;
#pragma unroll
        for (int n = 0; n < 4; ++n) po[n * 16 + li] = acc[m][n][r];
      }
    }
  }
#undef TILE_BODY
#undef STAGE_A
#undef STAGE_B
}

// ---------------- V transpose: (bh, n, 64) -> (bh, 64, n) ----------------
__global__ __launch_bounds__(256) void transpose_v(const u16* __restrict__ v, u16* __restrict__ vt) {
  __shared__ u16 tile[64][72];
  int bid = blockIdx.x;
  int bh = bid >> 6, n0 = (bid & 63) << 6;
  int t = threadIdx.x;
  int nl = t >> 2, ds = (t & 3) << 4;
  const u16* src = v + ((size_t)bh * 4096 + n0 + nl) * 64 + ds;
  *(uint4*)&tile[nl][ds] = *(const uint4*)src;
  *(uint4*)&tile[nl][ds + 8] = *(const uint4*)(src + 8);
  __syncthreads();
  int d = t >> 2, ns = (t & 3) << 4;
  ushort8 o0, o1;
#pragma unroll
  for (int e = 0; e < 8; ++e) { o0[e] = tile[ns + e][d]; o1[e] = tile[ns + 8 + e][d]; }
  u16* dst = vt + ((size_t)bh * 64 + d) * 4096 + n0 + ns;
  *(ushort8*)dst = o0;
  *(ushort8*)(dst + 8) = o1;
}

// ---------------- agent<-key flash attention (softmax over n), 8-way n-split ----------------
__global__ __launch_bounds__(256) void ak_flash(const u16* __restrict__ kb, const u16* __restrict__ vt,
                                                const u16* __restrict__ ab,
                                                float* __restrict__ pO, float* __restrict__ pM,
                                                float* __restrict__ pL) {
  __shared__ u16 p_lds[128][136];
  int bid = blockIdx.x;
  int s = bid & 7;
  int bh = bid >> 3;
  int h = bh & 15;
  int t = threadIdx.x, w = t >> 6, l = t & 63, lg = l >> 4, li = l & 15;
  int jb = w * 32;

  bf16x8 afr[2][2];
#pragma unroll
  for (int jt = 0; jt < 2; ++jt)
#pragma unroll
    for (int kk = 0; kk < 2; ++kk)
      afr[jt][kk] = *(const bf16x8*)&ab[(size_t)(h * 128 + jb + jt * 16 + li) * 64 + kk * 32 + lg * 8];

  f32x4 O[2][4];
  float mrow[2][4], lrow[2][4];
#pragma unroll
  for (int jt = 0; jt < 2; ++jt) {
#pragma unroll
    for (int dt = 0; dt < 4; ++dt) O[jt][dt] = (f32x4){0.f, 0.f, 0.f, 0.f};
#pragma unroll
    for (int r = 0; r < 4; ++r) { mrow[jt][r] = -1e30f; lrow[jt][r] = 0.f; }
  }
  const u16* kbase = kb + (size_t)bh * 4096 * 64;
  const u16* vbase = vt + (size_t)bh * 64 * 4096;

  for (int c = 0; c < 4; ++c) {
    int i0 = s * 512 + c * 128;
    f32x4 sf[2][8];
#pragma unroll
    for (int jt = 0; jt < 2; ++jt)
#pragma unroll
      for (int it = 0; it < 8; ++it) sf[jt][it] = (f32x4){0.f, 0.f, 0.f, 0.f};
#pragma unroll
    for (int it = 0; it < 8; ++it)
#pragma unroll
      for (int kk = 0; kk < 2; ++kk) {
        bf16x8 bfr = *(const bf16x8*)&kbase[(size_t)(i0 + it * 16 + li) * 64 + kk * 32 + lg * 8];
        sf[0][it] = MFMA16(afr[0][kk], bfr, sf[0][it]);
        sf[1][it] = MFMA16(afr[1][kk], bfr, sf[1][it]);
      }
#pragma unroll
    for (int jt = 0; jt < 2; ++jt)
#pragma unroll
      for (int r = 0; r < 4; ++r) {
        float cm = sf[jt][0][r];
#pragma unroll
        for (int it = 1; it < 8; ++it) cm = fmaxf(cm, sf[jt][it][r]);
#pragma unroll
        for (int off = 1; off < 16; off <<= 1) cm = fmaxf(cm, __shfl_xor(cm, off));
        float mold = mrow[jt][r];
        float mnew = fmaxf(mold, cm);
        float scale = __expf(mold - mnew);
        float ss = 0.f;
#pragma unroll
        for (int it = 0; it < 8; ++it) {
          float p = __expf(sf[jt][it][r] - mnew);
          sf[jt][it][r] = p;
          ss += p;
        }
#pragma unroll
        for (int off = 1; off < 16; off <<= 1) ss += __shfl_xor(ss, off);
        lrow[jt][r] = lrow[jt][r] * scale + ss;
        mrow[jt][r] = mnew;
#pragma unroll
        for (int dt = 0; dt < 4; ++dt) O[jt][dt][r] *= scale;
      }
#pragma unroll
    for (int jt = 0; jt < 2; ++jt)
#pragma unroll
      for (int it = 0; it < 8; ++it)
#pragma unroll
        for (int r = 0; r < 4; ++r)
          p_lds[jb + jt * 16 + lg * 4 + r][it * 16 + li] = f2bf(sf[jt][it][r]);
#pragma unroll
    for (int ks = 0; ks < 4; ++ks) {
      bf16x8 pa0 = *(const bf16x8*)&p_lds[jb + li][ks * 32 + lg * 8];
      bf16x8 pa1 = *(const bf16x8*)&p_lds[jb + 16 + li][ks * 32 + lg * 8];
#pragma unroll
      for (int dt = 0; dt < 4; ++dt) {
        bf16x8 bv = *(const bf16x8*)&vbase[(size_t)(dt * 16 + li) * 4096 + i0 + ks * 32 + lg * 8];
        O[0][dt] = MFMA16(pa0, bv, O[0][dt]);
        O[1][dt] = MFMA16(pa1, bv, O[1][dt]);
      }
    }
  }
  size_t pb = ((size_t)bh * 8 + s) * 128;
#pragma unroll
  for (int jt = 0; jt < 2; ++jt)
#pragma unroll
    for (int dt = 0; dt < 4; ++dt)
#pragma unroll
      for (int r = 0; r < 4; ++r) {
        int j = jb + jt * 16 + lg * 4 + r;
        pO[(pb + j) * 64 + dt * 16 + li] = O[jt][dt][r];
      }
  if (li == 0) {
#pragma unroll
    for (int jt = 0; jt < 2; ++jt)
#pragma unroll
      for (int r = 0; r < 4; ++r) {
        int j = jb + jt * 16 + lg * 4 + r;
        pM[pb + j] = mrow[jt][r];
        pL[pb + j] = lrow[jt][r];
      }
  }
}

__global__ __launch_bounds__(128) void ak_combine(const float* __restrict__ pO, const float* __restrict__ pM,
                                                  const float* __restrict__ pL, u16* __restrict__ out1t) {
  int bh = blockIdx.x;
  int j = threadIdx.x;
  float ms[8], wv[8];
  float M = -1e30f;
#pragma unroll
  for (int s = 0; s < 8; ++s) { ms[s] = pM[((size_t)bh * 8 + s) * 128 + j]; M = fmaxf(M, ms[s]); }
  float L = 0.f;
#pragma unroll
  for (int s = 0; s < 8; ++s) { wv[s] = __expf(ms[s] - M); L += wv[s] * pL[((size_t)bh * 8 + s) * 128 + j]; }
  float inv = 1.f / L;
  for (int d = 0; d < 64; ++d) {
    float acc = 0.f;
#pragma unroll
    for (int s = 0; s < 8; ++s) acc += wv[s] * pO[(((size_t)bh * 8 + s) * 128 + j) * 64 + d];
    out1t[((size_t)bh * 64 + d) * 128 + j] = f2bf(acc * inv);
  }
}

// ---------------- q<-agent attention fused with P@out1 ----------------
__global__ __launch_bounds__(256) void qa_fused(const u16* __restrict__ qb, const u16* __restrict__ out1t,
                                                const u16* __restrict__ ab, u16* __restrict__ out2) {
  __shared__ u16 p_lds[128][136];
  int bid = blockIdx.x;
  int nt = bid & 31;
  int bh = bid >> 5;
  int h = bh & 15, b = bh >> 4;
  int t = threadIdx.x, w = t >> 6, l = t & 63, lg = l >> 4, li = l & 15;
  int n0 = nt * 128;

  const u16* qbase = qb + ((size_t)bh * 4096 + n0 + w * 32) * 64;
  bf16x8 qf[2][2];
#pragma unroll
  for (int rt = 0; rt < 2; ++rt)
#pragma unroll
    for (int kk = 0; kk < 2; ++kk)
      qf[rt][kk] = *(const bf16x8*)&qbase[(size_t)(rt * 16 + li) * 64 + kk * 32 + lg * 8];

  f32x4 sf[2][8];
#pragma unroll
  for (int rt = 0; rt < 2; ++rt)
#pragma unroll
    for (int jt = 0; jt < 8; ++jt) sf[rt][jt] = (f32x4){0.f, 0.f, 0.f, 0.f};

  const u16* abase = ab + h * 128 * 64;
#pragma unroll
  for (int jt = 0; jt < 8; ++jt)
#pragma unroll
    for (int kk = 0; kk < 2; ++kk) {
      bf16x8 bfr = *(const bf16x8*)&abase[(size_t)(jt * 16 + li) * 64 + kk * 32 + lg * 8];
      sf[0][jt] = MFMA16(qf[0][kk], bfr, sf[0][jt]);
      sf[1][jt] = MFMA16(qf[1][kk], bfr, sf[1][jt]);
    }
  float inv[2][4];
#pragma unroll
  for (int rt = 0; rt < 2; ++rt)
#pragma unroll
    for (int r = 0; r < 4; ++r) {
      float cm = sf[rt][0][r];
#pragma unroll
      for (int jt = 1; jt < 8; ++jt) cm = fmaxf(cm, sf[rt][jt][r]);
#pragma unroll
      for (int off = 1; off < 16; off <<= 1) cm = fmaxf(cm, __shfl_xor(cm, off));
      float ss = 0.f;
#pragma unroll
      for (int jt = 0; jt < 8; ++jt) {
        float p = __expf(sf[rt][jt][r] - cm);
        sf[rt][jt][r] = p;
        ss += p;
      }
#pragma unroll
      for (int off = 1; off < 16; off <<= 1) ss += __shfl_xor(ss, off);
      inv[rt][r] = 1.f / ss;
    }
#pragma unroll
  for (int rt = 0; rt < 2; ++rt)
#pragma unroll
    for (int jt = 0; jt < 8; ++jt)
#pragma unroll
      for (int r = 0; r < 4; ++r)
        p_lds[w * 32 + rt * 16 + lg * 4 + r][jt * 16 + li] = f2bf(sf[rt][jt][r]);

  f32x4 O[2][4];
#pragma unroll
  for (int rt = 0; rt < 2; ++rt)
#pragma unroll
    for (int dt = 0; dt < 4; ++dt) O[rt][dt] = (f32x4){0.f, 0.f, 0.f, 0.f};

  const u16* obase = out1t + (size_t)bh * 64 * 128;
#pragma unroll
  for (int ks = 0; ks < 4; ++ks) {
    bf16x8 pa0 = *(const bf16x8*)&p_lds[w * 32 + li][ks * 32 + lg * 8];
    bf16x8 pa1 = *(const bf16x8*)&p_lds[w * 32 + 16 + li][ks * 32 + lg * 8];
#pragma unroll
    for (int dt = 0; dt < 4; ++dt) {
      bf16x8 bv = *(const bf16x8*)&obase[(size_t)(dt * 16 + li) * 128 + ks * 32 + lg * 8];
      O[0][dt] = MFMA16(pa0, bv, O[0][dt]);
      O[1][dt] = MFMA16(pa1, bv, O[1][dt]);
    }
  }
#pragma unroll
  for (int rt = 0; rt < 2; ++rt)
#pragma unroll
    for (int dt = 0; dt < 4; ++dt)
#pragma unroll
      for (int r = 0; r < 4; ++r) {
        int nn = n0 + w * 32 + rt * 16 + lg * 4 + r;
        int col = h * 64 + dt * 16 + li;
        out2[((size_t)b * 4096 + nn) * 1024 + col] = f2bf(O[rt][dt][r] * inv[rt][r]);
      }
}

// ---------------- launch ----------------
extern "C" void kernel_launch(void* const* d_in, const int* in_sizes, int n_in,
                              void* d_out, int out_size, void* d_ws, size_t ws_size,
                              hipStream_t stream) {
  const float* x = (const float*)d_in[0];
  const float* Wqkv = (const float*)d_in[1];
  const float* agent = (const float*)d_in[2];
  const float* Wout = (const float*)d_in[3];
  float* out = (float*)d_out;

  char* ws = (char*)d_ws;
  u16* x_bf  = (u16*)(ws + 0);
  u16* wqkvT = (u16*)(ws + 33554432);
  u16* woutT = (u16*)(ws + 39845888);
  u16* a_bf  = (u16*)(ws + 41943040);
  u16* qb    = (u16*)(ws + 42205184);
  u16* kb    = (u16*)(ws + 75759616);
  u16* vb    = (u16*)(ws + 109314048);
  u16* vt    = (u16*)(ws + 142868480);
  float* pO  = (float*)(ws + 176422912);
  float* pM  = (float*)(ws + 193200128);
  float* pL  = (float*)(ws + 193724416);
  u16* out1t = (u16*)(ws + 194248704);
  u16* out2  = x_bf;

  // allow 128 KB dynamic LDS (deterministic, capture-legal; ignore errors)
  (void)hipFuncSetAttribute((const void*)gemm256<0>, hipFuncAttributeMaxDynamicSharedMemorySize, 131072);
  (void)hipFuncSetAttribute((const void*)gemm256<1>, hipFuncAttributeMaxDynamicSharedMemorySize, 131072);

  conv_x_kernel<<<8192, 256, 0, stream>>>(x, x_bf);
  conv_wT_tiled<<<768, 256, 0, stream>>>(Wqkv, wqkvT, 1024, 3072);
  conv_wT_tiled<<<256, 256, 0, stream>>>(Wout, woutT, 1024, 1024);
  conv_a_kernel<<<512, 256, 0, stream>>>(agent, a_bf);

  gemm256<0><<<768, 512, 131072, stream>>>(x_bf, wqkvT, 16384, 3072, 1024, qb, kb, vb, nullptr);
  transpose_v<<<4096, 256, 0, stream>>>(vb, vt);
  ak_flash<<<512, 256, 0, stream>>>(kb, vt, a_bf, pO, pM, pL);
  ak_combine<<<64, 128, 0, stream>>>(pO, pM, pL, out1t);
  qa_fused<<<2048, 256, 0, stream>>>(qb, out1t, a_bf, out2);
  gemm256<1><<<256, 512, 131072, stream>>>(out2, woutT, 16384, 1024, 1024, nullptr, nullptr, nullptr, out);
}

// Round 3
// 299.141 us; speedup vs baseline: 1.2651x; 1.0137x over previous
//
#include <hip/hip_runtime.h>

typedef __bf16 bf16x8 __attribute__((ext_vector_type(8)));
typedef float f32x4 __attribute__((ext_vector_type(4)));
typedef unsigned short ushort8 __attribute__((ext_vector_type(8)));
typedef unsigned short u16;

#define MFMA16(a, b, c) __builtin_amdgcn_mfma_f32_16x16x32_bf16(a, b, c, 0, 0, 0)
#define VMCNT(n) asm volatile("s_waitcnt vmcnt(" #n ")" ::: "memory")
#define SBAR() do { __builtin_amdgcn_sched_barrier(0); asm volatile("" ::: "memory"); \
                    __builtin_amdgcn_s_barrier(); \
                    asm volatile("" ::: "memory"); __builtin_amdgcn_sched_barrier(0); } while (0)

__device__ __forceinline__ u16 f2bf(float v) {
  unsigned int u = __builtin_bit_cast(unsigned int, v);
  u += 0x7fffu + ((u >> 16) & 1u);   // RNE; inputs are finite
  return (u16)(u >> 16);
}

__device__ __forceinline__ void gload16(const u16* g, u16* l) {
  __builtin_amdgcn_global_load_lds((__attribute__((address_space(1))) void*)(g),
                                   (__attribute__((address_space(3))) void*)(l), 16, 0, 0);
}

// ---------------- converts ----------------

__global__ __launch_bounds__(256) void conv_x_kernel(const float* __restrict__ in, u16* __restrict__ out) {
  size_t i = (size_t)blockIdx.x * 256 + threadIdx.x;
  const float4* p = (const float4*)in + i * 2;
  float4 a = p[0], b = p[1];
  ushort8 o;
  o[0] = f2bf(a.x); o[1] = f2bf(a.y); o[2] = f2bf(a.z); o[3] = f2bf(a.w);
  o[4] = f2bf(b.x); o[5] = f2bf(b.y); o[6] = f2bf(b.z); o[7] = f2bf(b.w);
  *((ushort8*)out + i) = o;
}

// W: K x N (f32) -> WT: N x K (bf16), LDS-tiled 64x64, coalesced both sides.
__global__ __launch_bounds__(256) void conv_wT_tiled(const float* __restrict__ W, u16* __restrict__ WT,
                                                     int K, int N) {
  __shared__ float tile[64][65];
  int nt = N >> 6;
  int kt = blockIdx.x / nt, nti = blockIdx.x - kt * nt;
  int k0 = kt << 6, n0 = nti << 6;
  int t = threadIdx.x;
  int r = t >> 4, c4 = (t & 15) << 2;
#pragma unroll
  for (int j = 0; j < 4; ++j) {
    float4 v = *(const float4*)&W[(size_t)(k0 + j * 16 + r) * N + n0 + c4];
    tile[j * 16 + r][c4] = v.x; tile[j * 16 + r][c4 + 1] = v.y;
    tile[j * 16 + r][c4 + 2] = v.z; tile[j * 16 + r][c4 + 3] = v.w;
  }
  __syncthreads();
  int rn = t >> 2, cs = (t & 3) << 4;
  ushort8 o0, o1;
#pragma unroll
  for (int e = 0; e < 8; ++e) { o0[e] = f2bf(tile[cs + e][rn]); o1[e] = f2bf(tile[cs + 8 + e][rn]); }
  u16* dst = WT + (size_t)(n0 + rn) * K + k0 + cs;
  *(ushort8*)dst = o0;
  *(ushort8*)(dst + 8) = o1;
}

__global__ __launch_bounds__(256) void conv_a_kernel(const float* __restrict__ in, u16* __restrict__ out) {
  int i = blockIdx.x * 256 + threadIdx.x;
  out[i] = f2bf(in[i] * 0.125f);
}

// ---------------- 256^2 deep-pipelined GEMM, one-phase-ahead register prefetch ----------------
// A: M x K row-major bf16, BT: N x K row-major bf16. 512 thr = 8 waves (2Mx4N),
// per-wave C = 128x64. BK=32. LDS ring: 4 slots x (16KB A + 16KB B); stage t+3 during t.
// Phase = { [odd: vmcnt] barrier; issue ds_reads for NEXT phase; issue stage half;
//           sched_barrier; MFMA x16 on regs loaded LAST phase }.
// Reads drain during MFMA; compiler inserts the minimal lgkmcnt at next phase's use.
template <int MODE>
__global__ __launch_bounds__(512, 2) void gemm256(const u16* __restrict__ A, const u16* __restrict__ BT,
                                                  int M, int N, int K,
                                                  u16* __restrict__ qb, u16* __restrict__ kb,
                                                  u16* __restrict__ vb, float* __restrict__ outf) {
  extern __shared__ char smem[];   // 131072 bytes
  const int NT = K >> 5;           // 32 for both GEMMs
  int ntiles = N >> 8;
  int nwg = (M >> 8) * ntiles;
  int bid = blockIdx.x;
  int wg = (bid & 7) * (nwg >> 3) + (bid >> 3);   // XCD swizzle; nwg % 8 == 0 here
  int tm = wg / ntiles, tn = wg - tm * ntiles;
  int rb = tm << 8, cb = tn << 8;
  int t = threadIdx.x;
  int w = t >> 6, lane = t & 63, li = lane & 15, lg = lane >> 4;
  int wr = w >> 2, wc = w & 3;

  const u16* srcA[2];
  const u16* srcB[2];
#pragma unroll
  for (int j = 0; j < 2; ++j) {
    int D = j * 8192 + t * 16;
    int L = D ^ (((D >> 7) & 3) << 4);
    int row = L >> 6, inb = L & 63;
    srcA[j] = A + (size_t)(rb + row) * K + (inb >> 1);
    srcB[j] = BT + (size_t)(cb + row) * K + (inb >> 1);
  }
#define STAGE_A(slot, kt) do { \
    gload16(srcA[0] + (kt) * 32, (u16*)(smem + (slot) * 32768 + t * 16)); \
    gload16(srcA[1] + (kt) * 32, (u16*)(smem + (slot) * 32768 + 8192 + t * 16)); } while (0)
#define STAGE_B(slot, kt) do { \
    gload16(srcB[0] + (kt) * 32, (u16*)(smem + (slot) * 32768 + 16384 + t * 16)); \
    gload16(srcB[1] + (kt) * 32, (u16*)(smem + (slot) * 32768 + 24576 + t * 16)); } while (0)

  int offA[8], offB[4];
#pragma unroll
  for (int m8 = 0; m8 < 8; ++m8) {
    int row = wr * 128 + m8 * 16 + li;
    int L = row * 64 + lg * 16;
    offA[m8] = L ^ (((L >> 7) & 3) << 4);
  }
#pragma unroll
  for (int n = 0; n < 4; ++n) {
    int row = wc * 64 + n * 16 + li;
    int L = row * 64 + lg * 16;
    offB[n] = 16384 + (L ^ (((L >> 7) & 3) << 4));
  }

  f32x4 acc[8][4];
#pragma unroll
  for (int m = 0; m < 8; ++m)
#pragma unroll
    for (int n = 0; n < 4; ++n) acc[m][n] = (f32x4){0.f, 0.f, 0.f, 0.f};

  bf16x8 aF[4], aS[4], b0[4], b1[4];

#define RD_A_LO(sb, d) do { d[0] = *(const bf16x8*)((sb) + offA[0]); d[1] = *(const bf16x8*)((sb) + offA[1]); \
                            d[2] = *(const bf16x8*)((sb) + offA[2]); d[3] = *(const bf16x8*)((sb) + offA[3]); } while (0)
#define RD_A_HI(sb, d) do { d[0] = *(const bf16x8*)((sb) + offA[4]); d[1] = *(const bf16x8*)((sb) + offA[5]); \
                            d[2] = *(const bf16x8*)((sb) + offA[6]); d[3] = *(const bf16x8*)((sb) + offA[7]); } while (0)
#define RD_B(sb, d)    do { d[0] = *(const bf16x8*)((sb) + offB[0]); d[1] = *(const bf16x8*)((sb) + offB[1]); \
                            d[2] = *(const bf16x8*)((sb) + offB[2]); d[3] = *(const bf16x8*)((sb) + offB[3]); } while (0)

  // even phase of tile t: MFMA(aF, BC)->acc[0..3]; prefetch aS (slot t, A hi); stage A(t+3)
#define PH_EVEN(t, BC, STG) do { \
    SBAR(); \
    { char* sb_ = smem + ((t) & 3) * 32768; RD_A_HI(sb_, aS); } \
    if (STG) STAGE_A(((t) + 3) & 3, (t) + 3); \
    __builtin_amdgcn_sched_barrier(0); \
    __builtin_amdgcn_s_setprio(1); \
    _Pragma("unroll") for (int m = 0; m < 4; ++m) \
      _Pragma("unroll") for (int n = 0; n < 4; ++n) acc[m][n] = MFMA16(aF[m], BC[n], acc[m][n]); \
    __builtin_amdgcn_s_setprio(0); \
  } while (0)

  // odd phase of tile t: MFMA(aS, BC)->acc[4..7]; prefetch aF+BN (slot t+1); stage B(t+3)
#define PH_ODD(t, BC, BN, STG, RDNEXT, WAITOP) do { \
    WAITOP; \
    SBAR(); \
    if (RDNEXT) { char* sb_ = smem + (((t) + 1) & 3) * 32768; RD_A_LO(sb_, aF); RD_B(sb_, BN); } \
    if (STG) STAGE_B(((t) + 3) & 3, (t) + 3); \
    __builtin_amdgcn_sched_barrier(0); \
    __builtin_amdgcn_s_setprio(1); \
    _Pragma("unroll") for (int m = 0; m < 4; ++m) \
      _Pragma("unroll") for (int n = 0; n < 4; ++n) acc[4 + m][n] = MFMA16(aS[m], BC[n], acc[4 + m][n]); \
    __builtin_amdgcn_s_setprio(0); \
  } while (0)

#define TILE(t, BC, BN, STG, RDNEXT, WAITOP) do { \
    PH_EVEN(t, BC, STG); \
    PH_ODD(t, BC, BN, STG, RDNEXT, WAITOP); \
  } while (0)

  // prologue: stage tiles 0,1,2; wait tile0; preload first-phase frags
  STAGE_A(0, 0); STAGE_B(0, 0);
  STAGE_A(1, 1); STAGE_B(1, 1);
  STAGE_A(2, 2); STAGE_B(2, 2);
  VMCNT(8);
  SBAR();
  RD_A_LO(smem, aF); RD_B(smem, b0);

  // main: tiles 0..NT-5 staged, even count (NT=32 -> 0..27, 14 double-iters)
  for (int tt = 0; tt <= NT - 6; tt += 2) {
    TILE(tt,     b0, b1, 1, 1, VMCNT(6));
    TILE(tt + 1, b1, b0, 1, 1, VMCNT(6));
  }
  TILE(NT - 4, b0, b1, 1, 1, VMCNT(6));   // stages tile NT-1
  TILE(NT - 3, b1, b0, 0, 1, VMCNT(4));
  TILE(NT - 2, b0, b1, 0, 1, VMCNT(0));
  TILE(NT - 1, b1, b0, 0, 0, (void)0);

  if (MODE == 0) {
    int col0 = cb + wc * 64;
    int s = col0 >> 10, hh = (col0 >> 6) & 15;
    u16* dst = (s == 0) ? qb : ((s == 1) ? kb : vb);
#pragma unroll
    for (int m = 0; m < 8; ++m) {
      int rbase = rb + wr * 128 + m * 16 + lg * 4;
#pragma unroll
      for (int r = 0; r < 4; ++r) {
        int rr = rbase + r;
        size_t o = (((size_t)(rr >> 12) * 16 + hh) * 4096 + (rr & 4095)) * 64;
#pragma unroll
        for (int n = 0; n < 4; ++n) dst[o + n * 16 + li] = f2bf(acc[m][n][r]);
      }
    }
  } else {
#pragma unroll
    for (int m = 0; m < 8; ++m) {
#pragma unroll
      for (int r = 0; r < 4; ++r) {
        float* po = outf + (size_t)(rb + wr * 128 + m * 16 + lg * 4 + r) * N + cb + wc * 64;
#pragma unroll
        for (int n = 0; n < 4; ++n) po[n * 16 + li] = acc[m][n][r];
      }
    }
  }
#undef TILE
#undef PH_ODD
#undef PH_EVEN
#undef RD_A_LO
#undef RD_A_HI
#undef RD_B
#undef STAGE_A
#undef STAGE_B
}

// ---------------- V transpose: (bh, n, 64) -> (bh, 64, n) ----------------
__global__ __launch_bounds__(256) void transpose_v(const u16* __restrict__ v, u16* __restrict__ vt) {
  __shared__ u16 tile[64][72];
  int bid = blockIdx.x;
  int bh = bid >> 6, n0 = (bid & 63) << 6;
  int t = threadIdx.x;
  int nl = t >> 2, ds = (t & 3) << 4;
  const u16* src = v + ((size_t)bh * 4096 + n0 + nl) * 64 + ds;
  *(uint4*)&tile[nl][ds] = *(const uint4*)src;
  *(uint4*)&tile[nl][ds + 8] = *(const uint4*)(src + 8);
  __syncthreads();
  int d = t >> 2, ns = (t & 3) << 4;
  ushort8 o0, o1;
#pragma unroll
  for (int e = 0; e < 8; ++e) { o0[e] = tile[ns + e][d]; o1[e] = tile[ns + 8 + e][d]; }
  u16* dst = vt + ((size_t)bh * 64 + d) * 4096 + n0 + ns;
  *(ushort8*)dst = o0;
  *(ushort8*)(dst + 8) = o1;
}

// ---------------- agent<-key flash attention (softmax over n), 8-way n-split ----------------
__global__ __launch_bounds__(256) void ak_flash(const u16* __restrict__ kb, const u16* __restrict__ vt,
                                                const u16* __restrict__ ab,
                                                float* __restrict__ pO, float* __restrict__ pM,
                                                float* __restrict__ pL) {
  __shared__ u16 p_lds[128][136];
  int bid = blockIdx.x;
  int s = bid & 7;
  int bh = bid >> 3;
  int h = bh & 15;
  int t = threadIdx.x, w = t >> 6, l = t & 63, lg = l >> 4, li = l & 15;
  int jb = w * 32;

  bf16x8 afr[2][2];
#pragma unroll
  for (int jt = 0; jt < 2; ++jt)
#pragma unroll
    for (int kk = 0; kk < 2; ++kk)
      afr[jt][kk] = *(const bf16x8*)&ab[(size_t)(h * 128 + jb + jt * 16 + li) * 64 + kk * 32 + lg * 8];

  f32x4 O[2][4];
  float mrow[2][4], lrow[2][4];
#pragma unroll
  for (int jt = 0; jt < 2; ++jt) {
#pragma unroll
    for (int dt = 0; dt < 4; ++dt) O[jt][dt] = (f32x4){0.f, 0.f, 0.f, 0.f};
#pragma unroll
    for (int r = 0; r < 4; ++r) { mrow[jt][r] = -1e30f; lrow[jt][r] = 0.f; }
  }
  const u16* kbase = kb + (size_t)bh * 4096 * 64;
  const u16* vbase = vt + (size_t)bh * 64 * 4096;

  for (int c = 0; c < 4; ++c) {
    int i0 = s * 512 + c * 128;
    f32x4 sf[2][8];
#pragma unroll
    for (int jt = 0; jt < 2; ++jt)
#pragma unroll
      for (int it = 0; it < 8; ++it) sf[jt][it] = (f32x4){0.f, 0.f, 0.f, 0.f};
#pragma unroll
    for (int it = 0; it < 8; ++it)
#pragma unroll
      for (int kk = 0; kk < 2; ++kk) {
        bf16x8 bfr = *(const bf16x8*)&kbase[(size_t)(i0 + it * 16 + li) * 64 + kk * 32 + lg * 8];
        sf[0][it] = MFMA16(afr[0][kk], bfr, sf[0][it]);
        sf[1][it] = MFMA16(afr[1][kk], bfr, sf[1][it]);
      }
#pragma unroll
    for (int jt = 0; jt < 2; ++jt)
#pragma unroll
      for (int r = 0; r < 4; ++r) {
        float cm = sf[jt][0][r];
#pragma unroll
        for (int it = 1; it < 8; ++it) cm = fmaxf(cm, sf[jt][it][r]);
#pragma unroll
        for (int off = 1; off < 16; off <<= 1) cm = fmaxf(cm, __shfl_xor(cm, off));
        float mold = mrow[jt][r];
        float mnew = fmaxf(mold, cm);
        float scale = __expf(mold - mnew);
        float ss = 0.f;
#pragma unroll
        for (int it = 0; it < 8; ++it) {
          float p = __expf(sf[jt][it][r] - mnew);
          sf[jt][it][r] = p;
          ss += p;
        }
#pragma unroll
        for (int off = 1; off < 16; off <<= 1) ss += __shfl_xor(ss, off);
        lrow[jt][r] = lrow[jt][r] * scale + ss;
        mrow[jt][r] = mnew;
#pragma unroll
        for (int dt = 0; dt < 4; ++dt) O[jt][dt][r] *= scale;
      }
#pragma unroll
    for (int jt = 0; jt < 2; ++jt)
#pragma unroll
      for (int it = 0; it < 8; ++it)
#pragma unroll
        for (int r = 0; r < 4; ++r)
          p_lds[jb + jt * 16 + lg * 4 + r][it * 16 + li] = f2bf(sf[jt][it][r]);
#pragma unroll
    for (int ks = 0; ks < 4; ++ks) {
      bf16x8 pa0 = *(const bf16x8*)&p_lds[jb + li][ks * 32 + lg * 8];
      bf16x8 pa1 = *(const bf16x8*)&p_lds[jb + 16 + li][ks * 32 + lg * 8];
#pragma unroll
      for (int dt = 0; dt < 4; ++dt) {
        bf16x8 bv = *(const bf16x8*)&vbase[(size_t)(dt * 16 + li) * 4096 + i0 + ks * 32 + lg * 8];
        O[0][dt] = MFMA16(pa0, bv, O[0][dt]);
        O[1][dt] = MFMA16(pa1, bv, O[1][dt]);
      }
    }
  }
  size_t pb = ((size_t)bh * 8 + s) * 128;
#pragma unroll
  for (int jt = 0; jt < 2; ++jt)
#pragma unroll
    for (int dt = 0; dt < 4; ++dt)
#pragma unroll
      for (int r = 0; r < 4; ++r) {
        int j = jb + jt * 16 + lg * 4 + r;
        pO[(pb + j) * 64 + dt * 16 + li] = O[jt][dt][r];
      }
  if (li == 0) {
#pragma unroll
    for (int jt = 0; jt < 2; ++jt)
#pragma unroll
      for (int r = 0; r < 4; ++r) {
        int j = jb + jt * 16 + lg * 4 + r;
        pM[pb + j] = mrow[jt][r];
        pL[pb + j] = lrow[jt][r];
      }
  }
}

__global__ __launch_bounds__(128) void ak_combine(const float* __restrict__ pO, const float* __restrict__ pM,
                                                  const float* __restrict__ pL, u16* __restrict__ out1t) {
  int bh = blockIdx.x;
  int j = threadIdx.x;
  float ms[8], wv[8];
  float M = -1e30f;
#pragma unroll
  for (int s = 0; s < 8; ++s) { ms[s] = pM[((size_t)bh * 8 + s) * 128 + j]; M = fmaxf(M, ms[s]); }
  float L = 0.f;
#pragma unroll
  for (int s = 0; s < 8; ++s) { wv[s] = __expf(ms[s] - M); L += wv[s] * pL[((size_t)bh * 8 + s) * 128 + j]; }
  float inv = 1.f / L;
  for (int d = 0; d < 64; ++d) {
    float acc = 0.f;
#pragma unroll
    for (int s = 0; s < 8; ++s) acc += wv[s] * pO[(((size_t)bh * 8 + s) * 128 + j) * 64 + d];
    out1t[((size_t)bh * 64 + d) * 128 + j] = f2bf(acc * inv);
  }
}

// ---------------- q<-agent attention fused with P@out1 ----------------
__global__ __launch_bounds__(256) void qa_fused(const u16* __restrict__ qb, const u16* __restrict__ out1t,
                                                const u16* __restrict__ ab, u16* __restrict__ out2) {
  __shared__ u16 p_lds[128][136];
  int bid = blockIdx.x;
  int nt = bid & 31;
  int bh = bid >> 5;
  int h = bh & 15, b = bh >> 4;
  int t = threadIdx.x, w = t >> 6, l = t & 63, lg = l >> 4, li = l & 15;
  int n0 = nt * 128;

  const u16* qbase = qb + ((size_t)bh * 4096 + n0 + w * 32) * 64;
  bf16x8 qf[2][2];
#pragma unroll
  for (int rt = 0; rt < 2; ++rt)
#pragma unroll
    for (int kk = 0; kk < 2; ++kk)
      qf[rt][kk] = *(const bf16x8*)&qbase[(size_t)(rt * 16 + li) * 64 + kk * 32 + lg * 8];

  f32x4 sf[2][8];
#pragma unroll
  for (int rt = 0; rt < 2; ++rt)
#pragma unroll
    for (int jt = 0; jt < 8; ++jt) sf[rt][jt] = (f32x4){0.f, 0.f, 0.f, 0.f};

  const u16* abase = ab + h * 128 * 64;
#pragma unroll
  for (int jt = 0; jt < 8; ++jt)
#pragma unroll
    for (int kk = 0; kk < 2; ++kk) {
      bf16x8 bfr = *(const bf16x8*)&abase[(size_t)(jt * 16 + li) * 64 + kk * 32 + lg * 8];
      sf[0][jt] = MFMA16(qf[0][kk], bfr, sf[0][jt]);
      sf[1][jt] = MFMA16(qf[1][kk], bfr, sf[1][jt]);
    }
  float inv[2][4];
#pragma unroll
  for (int rt = 0; rt < 2; ++rt)
#pragma unroll
    for (int r = 0; r < 4; ++r) {
      float cm = sf[rt][0][r];
#pragma unroll
      for (int jt = 1; jt < 8; ++jt) cm = fmaxf(cm, sf[rt][jt][r]);
#pragma unroll
      for (int off = 1; off < 16; off <<= 1) cm = fmaxf(cm, __shfl_xor(cm, off));
      float ss = 0.f;
#pragma unroll
      for (int jt = 0; jt < 8; ++jt) {
        float p = __expf(sf[rt][jt][r] - cm);
        sf[rt][jt][r] = p;
        ss += p;
      }
#pragma unroll
      for (int off = 1; off < 16; off <<= 1) ss += __shfl_xor(ss, off);
      inv[rt][r] = 1.f / ss;
    }
#pragma unroll
  for (int rt = 0; rt < 2; ++rt)
#pragma unroll
    for (int jt = 0; jt < 8; ++jt)
#pragma unroll
      for (int r = 0; r < 4; ++r)
        p_lds[w * 32 + rt * 16 + lg * 4 + r][jt * 16 + li] = f2bf(sf[rt][jt][r]);

  f32x4 O[2][4];
#pragma unroll
  for (int rt = 0; rt < 2; ++rt)
#pragma unroll
    for (int dt = 0; dt < 4; ++dt) O[rt][dt] = (f32x4){0.f, 0.f, 0.f, 0.f};

  const u16* obase = out1t + (size_t)bh * 64 * 128;
#pragma unroll
  for (int ks = 0; ks < 4; ++ks) {
    bf16x8 pa0 = *(const bf16x8*)&p_lds[w * 32 + li][ks * 32 + lg * 8];
    bf16x8 pa1 = *(const bf16x8*)&p_lds[w * 32 + 16 + li][ks * 32 + lg * 8];
#pragma unroll
    for (int dt = 0; dt < 4; ++dt) {
      bf16x8 bv = *(const bf16x8*)&obase[(size_t)(dt * 16 + li) * 128 + ks * 32 + lg * 8];
      O[0][dt] = MFMA16(pa0, bv, O[0][dt]);
      O[1][dt] = MFMA16(pa1, bv, O[1][dt]);
    }
  }
#pragma unroll
  for (int rt = 0; rt < 2; ++rt)
#pragma unroll
    for (int dt = 0; dt < 4; ++dt)
#pragma unroll
      for (int r = 0; r < 4; ++r) {
        int nn = n0 + w * 32 + rt * 16 + lg * 4 + r;
        int col = h * 64 + dt * 16 + li;
        out2[((size_t)b * 4096 + nn) * 1024 + col] = f2bf(O[rt][dt][r] * inv[rt][r]);
      }
}

// ---------------- launch ----------------
extern "C" void kernel_launch(void* const* d_in, const int* in_sizes, int n_in,
                              void* d_out, int out_size, void* d_ws, size_t ws_size,
                              hipStream_t stream) {
  const float* x = (const float*)d_in[0];
  const float* Wqkv = (const float*)d_in[1];
  const float* agent = (const float*)d_in[2];
  const float* Wout = (const float*)d_in[3];
  float* out = (float*)d_out;

  char* ws = (char*)d_ws;
  u16* x_bf  = (u16*)(ws + 0);
  u16* wqkvT = (u16*)(ws + 33554432);
  u16* woutT = (u16*)(ws + 39845888);
  u16* a_bf  = (u16*)(ws + 41943040);
  u16* qb    = (u16*)(ws + 42205184);
  u16* kb    = (u16*)(ws + 75759616);
  u16* vb    = (u16*)(ws + 109314048);
  u16* vt    = (u16*)(ws + 142868480);
  float* pO  = (float*)(ws + 176422912);
  float* pM  = (float*)(ws + 193200128);
  float* pL  = (float*)(ws + 193724416);
  u16* out1t = (u16*)(ws + 194248704);
  u16* out2  = x_bf;

  (void)hipFuncSetAttribute((const void*)gemm256<0>, hipFuncAttributeMaxDynamicSharedMemorySize, 131072);
  (void)hipFuncSetAttribute((const void*)gemm256<1>, hipFuncAttributeMaxDynamicSharedMemorySize, 131072);

  conv_x_kernel<<<8192, 256, 0, stream>>>(x, x_bf);
  conv_wT_tiled<<<768, 256, 0, stream>>>(Wqkv, wqkvT, 1024, 3072);
  conv_wT_tiled<<<256, 256, 0, stream>>>(Wout, woutT, 1024, 1024);
  conv_a_kernel<<<512, 256, 0, stream>>>(agent, a_bf);

  gemm256<0><<<768, 512, 131072, stream>>>(x_bf, wqkvT, 16384, 3072, 1024, qb, kb, vb, nullptr);
  transpose_v<<<4096, 256, 0, stream>>>(vb, vt);
  ak_flash<<<512, 256, 0, stream>>>(kb, vt, a_bf, pO, pM, pL);
  ak_combine<<<64, 128, 0, stream>>>(pO, pM, pL, out1t);
  qa_fused<<<2048, 256, 0, stream>>>(qb, out1t, a_bf, out2);
  gemm256<1><<<256, 512, 131072, stream>>>(out2, woutT, 16384, 1024, 1024, nullptr, nullptr, nullptr, out);
}